// Round 4
// baseline (165.178 us; speedup 1.0000x reference)
//
#include <hip/hip_runtime.h>
#include <hip/hip_cooperative_groups.h>

namespace cg = cooperative_groups;

// Problem constants (reference: x = [8, 4096, 85] fp32)
constexpr int BS = 8;
constexpr int N  = 4096;
constexpr int F  = 85;
constexpr int NC = 80;          // classes = F - 5
constexpr float CONF_T = 0.65f;
constexpr float NMS_T  = 0.55f;
constexpr int MCAP = 256;       // per-(batch,class) member cap (mean ~18)
constexpr int NBLK = 256;       // one block per CU (cooperative co-residency)
constexpr int NTHR = 256;
constexpr int ROWS = 128;       // rows per block in phase 1 (NBLK*ROWS == BS*N)

// Single cooperative kernel, 3 phases separated by grid.sync():
//  P1 prep: LDS-staged coalesced read of x, per-row conf=max(cls scores)
//     (first-max), xyxy box, key = (~bits(conf))<<19 | idx<<7 | cls
//     (ascending key order == (conf desc, idx asc); idx unique -> cls in the
//     low bits never affects order; invalid: hi=0xFFFFFFFF, cls=127 sentinel).
//     Also zero-fills out rows and inits cnt[b]=N.
//  P2 rank: rank-by-count over LDS-resident keys (b128 broadcast reads);
//     scatters box/co/cls into rank order; cnt[b]=min rank of invalid = #valid.
//  P3 nms: one wave per (batch,class) pair; pipelined member collection into
//     a private LDS slice; wave-synchronous greedy suppression (reference IoU);
//     kept rows written straight to out[b*N+rank].
__global__ __launch_bounds__(NTHR) void fused_kernel(
        const float* __restrict__ x,
        unsigned long long* __restrict__ keys,
        float4* __restrict__ vbox,
        float2* __restrict__ vco,
        float4* __restrict__ rbox,
        float2* __restrict__ rco,
        int* __restrict__ rcls,
        unsigned* __restrict__ cnt,
        float4* __restrict__ out) {
    __shared__ __align__(16) char smem[ROWS * F * 4];   // 43,520 B (phase max)
    const int tid = threadIdx.x;
    const int blk = blockIdx.x;
    cg::grid_group grid = cg::this_grid();

    // ---------------- Phase 1: prep ----------------
    {
        float* sx = (float*)smem;
        const int row0 = blk * ROWS;
        const float4* src = (const float4*)(x + (size_t)row0 * F);  // 16B-aligned
        float4* dst = (float4*)sx;
        constexpr int NV4 = ROWS * F / 4;               // 2720
        for (int i = tid; i < NV4; i += NTHR) dst[i] = src[i];
        // zero this block's 128 output rows (2 float4 each, covered once/grid)
        out[(size_t)row0 * 2 + tid] = make_float4(0.f, 0.f, 0.f, 0.f);
        if (blk < BS && tid == 0) cnt[blk] = N;
        __syncthreads();
        if (tid < ROWS) {
            const float* p = sx + tid * F;              // stride 85: 2-way alias (free)
            float cx = p[0], cy = p[1], w = p[2], h = p[3], obj = p[4];
            float best = p[5];
            int bi = 0;
            #pragma unroll 8
            for (int c = 1; c < NC; ++c) {
                float v = p[5 + c];
                if (v > best) { best = v; bi = c; }     // strict >: first max (jnp.argmax)
            }
            const int t = row0 + tid;
            const bool valid = obj > CONF_T;
            unsigned hi = valid ? ~__float_as_uint(best) : 0xFFFFFFFFu;
            unsigned cl = valid ? (unsigned)bi : 127u;
            keys[t] = ((unsigned long long)hi << 19)
                    | ((unsigned long long)(unsigned)(t & (N - 1)) << 7) | cl;
            vbox[t] = make_float4(cx - w * 0.5f, cy - h * 0.5f,
                                  cx + w * 0.5f, cy + h * 0.5f);
            vco[t]  = make_float2(obj, best);
        }
    }
    grid.sync();

    // ---------------- Phase 2: rank-by-count + scatter ----------------
    {
        unsigned long long* sk = (unsigned long long*)smem;   // 32,768 B
        int* partial = (int*)(smem + 32768);                  // 512 B
        const int b  = blk >> 5;
        const int c0 = (blk & 31) * 128;
        const unsigned long long* kb = keys + (size_t)b * N;
        for (int i = tid; i < N / 2; i += NTHR)
            ((ulonglong2*)sk)[i] = ((const ulonglong2*)kb)[i];
        __syncthreads();
        const int li = tid & 127;                       // box within this block's chunk
        const int s  = tid >> 7;                        // half selector
        const unsigned long long myk = sk[c0 + li];
        const ulonglong2* half = (const ulonglong2*)sk + s * (N / 4);
        int cr = 0;
        #pragma unroll 8
        for (int j = 0; j < N / 4; ++j) {               // b128 broadcast reads
            ulonglong2 kk = half[j];
            cr += (kk.x < myk) ? 1 : 0;
            cr += (kk.y < myk) ? 1 : 0;
        }
        if (s) partial[li] = cr;
        __syncthreads();
        if (!s) {
            int rank = cr + partial[li];                // exact stable desc-conf rank
            int src = b * N + c0 + li;
            int d   = b * N + rank;
            rbox[d] = vbox[src];
            rco[d]  = vco[src];
            rcls[d] = (int)(myk & 127u);                // 127 sentinel for invalid
            if ((myk >> 19) == 0xFFFFFFFFull)           // invalid: rank >= #valid
                atomicMin(&cnt[b], (unsigned)rank);     // min = #valid boxes
        }
    }
    grid.sync();

    // ---------------- Phase 3: per-(batch,class) NMS, one wave each ----------------
    {
        const int w = tid >> 6, lane = tid & 63;
        char* sl = smem + w * 5120;                     // private per-wave slice
        float4* sbox = (float4*)sl;                     // 4096 B
        unsigned short* srank = (unsigned short*)(sl + 4096);  // 512 B
        unsigned char* srem = (unsigned char*)(sl + 4608);     // 256 B
        for (int pair = blk * 4 + w; pair < BS * NC; pair += NBLK * 4) {
            const int b = pair / NC, c = pair - b * NC;
            const int bN = b * N;
            const int nv = (int)cnt[b];

            // member collection (rank order), software-pipelined loads
            int r0 = bN + lane;
            int cv = rcls[r0];
            float4 bx = rbox[r0];
            if (lane >= nv) cv = -1;
            int n = 0;
            for (int base = 0; base < nv; base += 64) {
                int rn = base + 64 + lane;
                int rc = bN + (rn & (N - 1));           // clamped, always in-bounds
                int cvn = rcls[rc];                     // prefetch next chunk
                float4 bxn = rbox[rc];
                if (rn >= nv) cvn = -1;
                bool member = (cv == c);
                unsigned long long mb = __ballot(member);
                if (member) {
                    int pos = n + __popcll(mb & ((1ull << lane) - 1ull));
                    if (pos < MCAP) {
                        sbox[pos]  = bx;
                        srank[pos] = (unsigned short)(base + lane);
                    }
                }
                n += __popcll(mb);
                cv = cvn;
                bx = bxn;
            }
            if (n > MCAP) n = MCAP;
            for (int j = lane; j < n; j += 64) srem[j] = 0;

            // wave-synchronous greedy (single wave owns this LDS slice)
            for (int i = 0; i < n; ++i) {
                if (srem[i]) continue;                  // same address: wave-uniform
                float4 bi4 = sbox[i];
                float ai = (bi4.z - bi4.x) * (bi4.w - bi4.y);
                for (int j = i + 1 + lane; j < n; j += 64) {
                    if (!srem[j]) {
                        float4 bj = sbox[j];
                        float ix1 = fmaxf(bi4.x, bj.x);
                        float iy1 = fmaxf(bi4.y, bj.y);
                        float ix2 = fminf(bi4.z, bj.z);
                        float iy2 = fminf(bi4.w, bj.w);
                        float inter = fmaxf(ix2 - ix1, 0.0f) * fmaxf(iy2 - iy1, 0.0f);
                        float aj = (bj.z - bj.x) * (bj.w - bj.y);
                        float iou = inter / (ai + aj - inter + 1e-16f);
                        if (iou > NMS_T) srem[j] = 1;
                    }
                }
            }

            // emit kept rows
            for (int j = lane; j < n; j += 64) {
                if (!srem[j]) {
                    int r = srank[j];
                    float4 bq = sbox[j];
                    float2 oc = rco[bN + r];
                    float4* o = out + (size_t)(bN + r) * 2;
                    o[0] = make_float4((float)b, bq.x, bq.y, bq.z);
                    o[1] = make_float4(bq.w, oc.x, oc.y, (float)c);
                }
            }
        }
    }
}

extern "C" void kernel_launch(void* const* d_in, const int* in_sizes, int n_in,
                              void* d_out, int out_size, void* d_ws, size_t ws_size,
                              hipStream_t stream) {
    const float* x = (const float*)d_in[0];
    float4* out = (float4*)d_out;

    char* ws = (char*)d_ws;
    size_t off = 0;
    auto alloc = [&](size_t bytes) { char* p = ws + off; off += (bytes + 255) & ~255ull; return p; };
    unsigned long long* keys = (unsigned long long*)alloc(BS * N * 8);   // 256 KB
    float4*   vbox = (float4*)alloc(BS * N * 16);                         // 512 KB
    float2*   vco  = (float2*)alloc(BS * N * 8);                          // 256 KB
    float4*   rbox = (float4*)alloc(BS * N * 16);                         // 512 KB
    float2*   rco  = (float2*)alloc(BS * N * 8);                          // 256 KB
    int*      rcls = (int*)alloc(BS * N * 4);                             // 128 KB
    unsigned* cnt  = (unsigned*)alloc(BS * 4);                            // 32 B

    void* args[] = {(void*)&x, (void*)&keys, (void*)&vbox, (void*)&vco,
                    (void*)&rbox, (void*)&rco, (void*)&rcls, (void*)&cnt,
                    (void*)&out};
    hipLaunchCooperativeKernel((const void*)fused_kernel, dim3(NBLK), dim3(NTHR),
                               args, 0, stream);
}

// Round 5
// 100.285 us; speedup vs baseline: 1.6471x; 1.6471x over previous
//
#include <hip/hip_runtime.h>

// Problem constants (reference: x = [8, 4096, 85] fp32)
constexpr int BS = 8;
constexpr int N  = 4096;
constexpr int F  = 85;
constexpr int NC = 80;          // classes = F - 5
constexpr float CONF_T = 0.65f;
constexpr float NMS_T  = 0.55f;
constexpr int MCAP = 256;       // per-(batch,class) member cap (mean ~18)
constexpr int SEGS = 32;        // prep blocks (segments) per batch
constexpr int SEGR = 128;       // rows per segment

// key = (~bits(conf))<<19 | idx<<7 | cls.  Ascending key order == (conf desc,
// idx asc) == reference's stable argsort; idx unique so cls bits never affect
// order. Only VALID boxes get keys (segmented compact layout).

// ---------------- K1: prep (LDS-staged read, split argmax, segment compact) ----
__global__ __launch_bounds__(256) void prep_kernel(
        const float* __restrict__ x,
        unsigned long long* __restrict__ gkeys,   // [BS][SEGS*128] segmented
        float4* __restrict__ vbox,                // [BS*N] by original idx
        float2* __restrict__ vco,                 // (obj, conf)
        int* __restrict__ cntblk,                 // [BS*SEGS] per-segment count
        float4* __restrict__ out) {
    __shared__ __align__(16) float sx[SEGR * F];  // 43,520 B
    __shared__ float sbest2[SEGR];
    __shared__ int   sbi2[SEGR];
    __shared__ int   wq[4];
    const int tid = threadIdx.x, blk = blockIdx.x;
    const int row0 = blk * SEGR;
    // coalesced staging: row0*F*4 = blk*43520 bytes, 16B-aligned
    const float4* src = (const float4*)(x + (size_t)row0 * F);
    float4* dst = (float4*)sx;
    constexpr int NV4 = SEGR * F / 4;             // 2720
    for (int i = tid; i < NV4; i += 256) dst[i] = src[i];
    // zero this block's 128 output rows (2 float4 each, covered once per grid)
    out[(size_t)row0 * 2 + tid] = make_float4(0.f, 0.f, 0.f, 0.f);
    __syncthreads();

    // split argmax: thread (r, h) scans classes h*40..h*40+39 of row r
    const int r = tid & 127;
    const int h = tid >> 7;
    float mybest; int mybi;
    {
        const float* p = sx + r * F + 5 + h * 40;
        float best = p[0]; int bi = 0;
        #pragma unroll 8
        for (int c = 1; c < 40; ++c) {
            float v = p[c];
            if (v > best) { best = v; bi = c; }   // strict >: first max
        }
        mybest = best; mybi = bi + h * 40;
        if (h) { sbest2[r] = best; sbi2[r] = mybi; }
    }
    __syncthreads();

    bool valid = false;
    unsigned long long key = 0;
    if (!h) {
        float b1 = sbest2[r];
        if (b1 > mybest) { mybest = b1; mybi = sbi2[r]; }  // low half wins ties
        const float* p = sx + r * F;
        float cx = p[0], cy = p[1], w = p[2], hh = p[3], obj = p[4];
        const int t = row0 + r;
        vbox[t] = make_float4(cx - w * 0.5f, cy - hh * 0.5f,
                              cx + w * 0.5f, cy + hh * 0.5f);
        vco[t]  = make_float2(obj, mybest);
        valid = obj > CONF_T;
        key = ((unsigned long long)(~__float_as_uint(mybest)) << 19)
            | ((unsigned long long)(unsigned)(t & (N - 1)) << 7)
            | (unsigned)mybi;
    }
    // block-local compaction (waves 2,3 contribute zero)
    const int lane = tid & 63, w = tid >> 6;
    unsigned long long mask = __ballot(valid);
    if (lane == 0) wq[w] = __popcll(mask);
    __syncthreads();
    int base = 0;
    for (int i = 0; i < w; ++i) base += wq[i];
    if (valid) {
        int slot = base + __popcll(mask & ((1ull << lane) - 1ull));
        gkeys[((size_t)(blk >> 5) << 12) + ((blk & 31) << 7) + slot] = key;
    }
    if (tid == 0) cntblk[blk] = wq[0] + wq[1];
}

// ---------------- K2: rank-by-count over valid keys only ----------------
// grid (64, BS) x 256. Block ranks 64 compact boxes (4 threads each scan a
// quarter of the packed keys via b128 broadcast LDS reads). Packs the 32
// segments contiguously into LDS first; writes cnt[b]=nv for nms.
__global__ __launch_bounds__(256) void rank_kernel(
        const unsigned long long* __restrict__ gkeys,
        const float4* __restrict__ vbox,
        const float2* __restrict__ vco,
        const int* __restrict__ cntblk,
        float4* __restrict__ rbox,
        float2* __restrict__ rco,
        int* __restrict__ rcls,
        int* __restrict__ cnt) {
    __shared__ __align__(16) unsigned long long sk[N + 2];
    __shared__ int scnt[SEGS];
    __shared__ int part[256];
    const int b = blockIdx.y, tid = threadIdx.x;
    if (tid < SEGS) scnt[tid] = cntblk[b * SEGS + tid];
    __syncthreads();
    int nv = 0;
    #pragma unroll
    for (int s = 0; s < SEGS; ++s) nv += scnt[s];     // broadcast reads
    if (blockIdx.x == 0 && tid == 0) cnt[b] = nv;
    const int c0 = blockIdx.x * 64;
    if (c0 >= nv) return;                              // block-uniform exit

    // pack segments contiguously (coalesced global b64 loads)
    const unsigned long long* kb = gkeys + ((size_t)b << 12);
    int pbase = 0;
    for (int s = 0; s < SEGS; ++s) {
        int c = scnt[s];
        for (int j = tid; j < c; j += 256) sk[pbase + j] = kb[(s << 7) + j];
        pbase += c;
    }
    if (tid == 0) { sk[nv] = ~0ull; sk[nv + 1] = ~0ull; }  // pair-read pad
    __syncthreads();

    const int li = tid & 63, q = tid >> 6;
    const int bi = c0 + li;
    const bool active = bi < nv;
    const unsigned long long myk = active ? sk[bi] : 0;
    const int P = (nv + 1) >> 1;                       // u64 pairs
    const int j0 = (P * q) >> 2, j1 = (P * (q + 1)) >> 2;
    const ulonglong2* skp = (const ulonglong2*)sk;
    int cr = 0;
    for (int j = j0; j < j1; ++j) {                    // b128 broadcast reads
        ulonglong2 kk = skp[j];
        cr += (kk.x < myk) ? 1 : 0;
        cr += (kk.y < myk) ? 1 : 0;
    }
    part[tid] = cr;
    __syncthreads();
    if (q == 0 && active) {
        int rank = part[li] + part[li + 64] + part[li + 128] + part[li + 192];
        int idx = (int)((myk >> 7) & (N - 1));
        int s = (b << 12) + idx;
        int d = (b << 12) + rank;                      // exact stable rank
        rbox[d] = vbox[s];
        rco[d]  = vco[s];
        rcls[d] = (int)(myk & 127u);
    }
}

// ---------------- K3: per-(batch,class) greedy NMS + emit ----------------
// grid (NC, BS), one wave. Pipelined member collection (known trip count),
// wave-synchronous greedy suppression (reference IoU), direct row emit.
__global__ __launch_bounds__(64) void nms_kernel(
        const float4* __restrict__ rbox,
        const float2* __restrict__ rco,
        const int* __restrict__ rcls,
        const int* __restrict__ cnt,
        float4* __restrict__ out) {
    __shared__ float4 sbox[MCAP];
    __shared__ unsigned short srank[MCAP];
    __shared__ unsigned char srem[MCAP];
    const int c = blockIdx.x, b = blockIdx.y, lane = threadIdx.x;
    const int bN = b << 12;
    const int nv = cnt[b];

    int cv; float4 bx;
    {
        int rr = bN + (lane < nv ? lane : 0);
        cv = rcls[rr]; bx = rbox[rr];
        if (lane >= nv) cv = -1;
    }
    int n = 0;
    for (int base = 0; base < nv; base += 64) {
        int rn = base + 64 + lane;
        int rc = bN + (rn < nv ? rn : 0);
        int cvn = rcls[rc];                            // prefetch next chunk
        float4 bxn = rbox[rc];
        if (rn >= nv) cvn = -1;
        bool member = (cv == c);
        unsigned long long mb = __ballot(member);
        if (member) {
            int pos = n + __popcll(mb & ((1ull << lane) - 1ull));
            if (pos < MCAP) {
                sbox[pos]  = bx;
                srank[pos] = (unsigned short)(base + lane);
            }
        }
        n += __popcll(mb);
        cv = cvn; bx = bxn;
    }
    if (n > MCAP) n = MCAP;
    for (int j = lane; j < n; j += 64) srem[j] = 0;

    // single wave owns the LDS: wave-synchronous, no barriers needed
    for (int i = 0; i < n; ++i) {
        if (srem[i]) continue;                         // same address: uniform
        float4 bi4 = sbox[i];
        float ai = (bi4.z - bi4.x) * (bi4.w - bi4.y);
        for (int j = i + 1 + lane; j < n; j += 64) {
            if (!srem[j]) {
                float4 bj = sbox[j];
                float ix1 = fmaxf(bi4.x, bj.x);
                float iy1 = fmaxf(bi4.y, bj.y);
                float ix2 = fminf(bi4.z, bj.z);
                float iy2 = fminf(bi4.w, bj.w);
                float inter = fmaxf(ix2 - ix1, 0.0f) * fmaxf(iy2 - iy1, 0.0f);
                float aj = (bj.z - bj.x) * (bj.w - bj.y);
                float iou = inter / (ai + aj - inter + 1e-16f);
                if (iou > NMS_T) srem[j] = 1;
            }
        }
    }
    for (int j = lane; j < n; j += 64) {
        if (!srem[j]) {
            int rr = srank[j];
            float4 bq = sbox[j];
            float2 oc = rco[bN + rr];
            float4* o = out + (size_t)(bN + rr) * 2;
            o[0] = make_float4((float)b, bq.x, bq.y, bq.z);
            o[1] = make_float4(bq.w, oc.x, oc.y, (float)c);
        }
    }
}

extern "C" void kernel_launch(void* const* d_in, const int* in_sizes, int n_in,
                              void* d_out, int out_size, void* d_ws, size_t ws_size,
                              hipStream_t stream) {
    const float* x = (const float*)d_in[0];
    float4* out = (float4*)d_out;

    char* ws = (char*)d_ws;
    size_t off = 0;
    auto alloc = [&](size_t bytes) { char* p = ws + off; off += (bytes + 255) & ~255ull; return p; };
    unsigned long long* gkeys = (unsigned long long*)alloc(BS * N * 8);  // 256 KB
    float4* vbox = (float4*)alloc(BS * N * 16);                           // 512 KB
    float2* vco  = (float2*)alloc(BS * N * 8);                            // 256 KB
    int*    cntblk = (int*)alloc(BS * SEGS * 4);                          // 1 KB
    float4* rbox = (float4*)alloc(BS * N * 16);                           // 512 KB
    float2* rco  = (float2*)alloc(BS * N * 8);                            // 256 KB
    int*    rcls = (int*)alloc(BS * N * 4);                               // 128 KB
    int*    cnt  = (int*)alloc(BS * 4);                                   // 32 B

    prep_kernel<<<BS * N / SEGR, 256, 0, stream>>>(x, gkeys, vbox, vco, cntblk, out);
    rank_kernel<<<dim3(64, BS), 256, 0, stream>>>(gkeys, vbox, vco, cntblk,
                                                  rbox, rco, rcls, cnt);
    nms_kernel<<<dim3(NC, BS), 64, 0, stream>>>(rbox, rco, rcls, cnt, out);
}